// Round 2
// 1017.051 us; speedup vs baseline: 2.0558x; 2.0558x over previous
//
#include <hip/hip_runtime.h>

// ---------------------------------------------------------------------------
// PerTokenFN: out[b,t,:] = GELU(x[b,t,:] @ W1[t] + b1[t]) @ W2[t] + b2[t]
// B=4096, T=64, D=256, H=1024.  fp32 in/out, bf16 MFMA compute.
//
// Round-3 build (hardened round-2):
//  * prepass kernels convert W1/W2 fp32 -> bf16 ONCE into d_ws, laid out as
//    the exact swizzled per-K-step LDS images the main loop reads.
//  * main kernel stages weights with global_load_lds (16B DMA, linear dest,
//    pre-swizzled source), double-buffered, counted s_waitcnt vmcnt(N) + raw
//    s_barrier (never vmcnt(0) mid-loop), s_setprio(1) around MFMA clusters.
//  * NEW: compiler memory fences on both sides of every raw s_barrier
//    (s_barrier is not an LLVM fence; prevents ds_read hoisting across it).
//  * NEW: amdgpu_waves_per_eu(2,2) pins the allocator at the 256-VGPR budget
//    (round-0 squeezed to 124 VGPR and spilled ~77MB of scratch).
//  * falls back to the round-0 verified kernel if ws_size < 64 MB.
// ---------------------------------------------------------------------------

typedef __bf16 bf16x8 __attribute__((ext_vector_type(8)));
typedef float  floatx4 __attribute__((ext_vector_type(4)));

__device__ __forceinline__ unsigned short f2bf(float f) {
  unsigned u = __builtin_bit_cast(unsigned, f);
  u += 0x7fffu + ((u >> 16) & 1u);   // RNE
  return (unsigned short)(u >> 16);
}

__device__ __forceinline__ float gelu_exact(float v) {
  return 0.5f * v * (1.0f + erff(v * 0.70710678118654752f));
}

// global->LDS DMA, 16B per lane. LDS dest must be wave-uniform; generic LDS
// address low 32 bits == LDS offset on AMDGPU (shared aperture is 4GB-aligned).
__device__ __forceinline__ void gll16(const void* g, void* l) {
  __builtin_amdgcn_global_load_lds(
      (const __attribute__((address_space(1))) unsigned*)g,
      (__attribute__((address_space(3))) unsigned*)(unsigned)(unsigned long long)l,
      16, 0, 0);
}

// raw workgroup barrier with compiler fences on both sides: no memory op may
// be hoisted or sunk across it by the scheduler (s_barrier alone is not an
// LLVM memory fence).
__device__ __forceinline__ void barrier_fenced() {
  asm volatile("" ::: "memory");
  __builtin_amdgcn_s_barrier();
  asm volatile("" ::: "memory");
}

// ---------------------------------------------------------------------------
// Image layouts (byte offsets inside one K-step image):
//  W1 image (8 KB, per (t,c,kk)):  elem(jl in[0,128), dl=q*8+i) at
//      jl*64 + (q ^ ((jl>>1)&3))*16 + i*2,   d = kk*32+dl, h = c*128+jl
//  W2 image (16 KB, per (t,c,kk2)): elem(d in[0,256), jl32=q*8+i) at
//      d*64 + (q ^ ((d>>1)&3))*16 + i*2,     j = c*128+kk2*32+jl32
// Identical to the LDS images the round-0 verified kernel built on the fly.
// ---------------------------------------------------------------------------

// W1 fp32 [t][d=256][h=1024] -> bf16 images [t][c=8][kk=8][8KB]
__global__ __launch_bounds__(256) void prep_w1(const float* __restrict__ w1,
                                               unsigned short* __restrict__ img) {
  const int idx  = blockIdx.x * 256 + threadIdx.x;  // one 16B slot, 2^21 total
  const int slot = idx & 511;
  const int im   = idx >> 9;                        // ((t*8 + c)*8 + kk)
  const int jl = slot >> 2, m = slot & 3;
  const int kk = im & 7, c = (im >> 3) & 7, t = im >> 6;
  const int q  = m ^ ((jl >> 1) & 3);
  const float* src = w1 + (size_t)t * 262144 +
                     (size_t)(kk * 32 + q * 8) * 1024 + c * 128 + jl;
  union { uint4 v; unsigned short s[8]; } o;
#pragma unroll
  for (int i = 0; i < 8; ++i) o.s[i] = f2bf(src[(size_t)i * 1024]);
  *(uint4*)(img + (size_t)idx * 8) = o.v;
}

// W2 fp32 [t][h=1024][d=256] -> bf16 images [t][c=8][kk2=4][16KB]
__global__ __launch_bounds__(256) void prep_w2(const float* __restrict__ w2,
                                               unsigned short* __restrict__ img) {
  const int idx  = blockIdx.x * 256 + threadIdx.x;  // 2^21 slots
  const int slot = idx & 1023;
  const int im   = idx >> 10;                       // ((t*8 + c)*4 + kk2)
  const int d = slot >> 2, m = slot & 3;
  const int kk2 = im & 3, c = (im >> 2) & 7, t = im >> 5;
  const int q   = m ^ ((d >> 1) & 3);
  const float* src = w2 + (size_t)t * 262144 +
                     (size_t)(c * 128 + kk2 * 32 + q * 8) * 256 + d;
  union { uint4 v; unsigned short s[8]; } o;
#pragma unroll
  for (int i = 0; i < 8; ++i) o.s[i] = f2bf(src[(size_t)i * 256]);
  *(uint4*)(img + (size_t)idx * 8) = o.v;
}

// ---------------------------------------------------------------------------
// Main kernel: pipelined item sequence per chunk c: W1k0..7, W2k0..3.
// At each step n: issue stage(n+1) -> s_waitcnt vmcnt(|batch n+1|) (drains
// batch n, which is strictly older) -> barrier -> ds_read frags + MFMA(n)
// -> barrier (readers done; buffer n's slot reusable).
// Ledger safety: each wait only asserts "all ops older than the just-issued
// batch have landed"; vmem completes in order, so compiler-inserted extra
// vmem ops can only make waits stricter, never unsound.
// ---------------------------------------------------------------------------
__global__ __launch_bounds__(256)
__attribute__((amdgpu_waves_per_eu(2, 2)))
void mlp_fast(
    const float* __restrict__ x, const unsigned short* __restrict__ w1i,
    const float* __restrict__ b1, const unsigned short* __restrict__ w2i,
    const float* __restrict__ b2, float* __restrict__ out) {

  __shared__ __attribute__((aligned(16))) unsigned char lds[69632];
  unsigned char* const w1b0 = lds;             // [0, 8K)
  unsigned char* const w1b1 = lds + 8192;      // [8K, 16K)
  unsigned char* const w2b0 = lds + 16384;     // [16K, 32K)
  unsigned char* const w2b1 = lds + 32768;     // [32K, 48K)
  unsigned char* const hlds = lds + 49152;     // [48K, 64K)
  float* const b1lds = (float*)(lds + 65536);  // [64K, 68K)

  const int tid  = threadIdx.x;
  const int lane = tid & 63;
  const int w    = tid >> 6;        // 0..3
  const int wm   = w >> 1;
  const int wn   = w & 1;
  const int l15  = lane & 15;
  const int l4   = lane >> 4;

  const int bid  = blockIdx.x;
  const int t    = (bid & 7) + 8 * (bid >> 9);   // t pinned per XCD
  const int b0   = ((bid >> 3) & 63) << 6;

  const unsigned char* w1t = (const unsigned char*)(w1i + (size_t)t * 262144);
  const unsigned char* w2t = (const unsigned char*)(w2i + (size_t)t * 262144);
  const int lo16 = lane * 16;

  // ---- b1 -> LDS once ----
#pragma unroll
  for (int i = 0; i < 4; ++i)
    b1lds[tid + 256 * i] = b1[t * 1024 + tid + 256 * i];

  // ---- x fragments: A-operand of GEMM1, in registers ----
  bf16x8 xfrag[2][8];
#pragma unroll
  for (int mt = 0; mt < 2; ++mt) {
    const int b = b0 + wm * 32 + mt * 16 + l15;
    const float* xb = x + ((size_t)b * 64 + t) * 256 + l4 * 8;
#pragma unroll
    for (int kk = 0; kk < 8; ++kk) {
      floatx4 lo = *(const floatx4*)(xb + kk * 32);
      floatx4 hi = *(const floatx4*)(xb + kk * 32 + 4);
      union { bf16x8 v; unsigned short s[8]; } px;
      px.s[0] = f2bf(lo[0]); px.s[1] = f2bf(lo[1]);
      px.s[2] = f2bf(lo[2]); px.s[3] = f2bf(lo[3]);
      px.s[4] = f2bf(hi[0]); px.s[5] = f2bf(hi[1]);
      px.s[6] = f2bf(hi[2]); px.s[7] = f2bf(hi[3]);
      xfrag[mt][kk] = px.v;
    }
  }

  // ---- out^T accumulators, init with b2 ----
  floatx4 oacc[4][4];
#pragma unroll
  for (int mt = 0; mt < 4; ++mt) {
    const floatx4 bv = *(const floatx4*)(b2 + t * 256 + w * 64 + mt * 16 + l4 * 4);
#pragma unroll
    for (int nt = 0; nt < 4; ++nt) oacc[mt][nt] = bv;
  }

  const int swf    = (l4 ^ ((lane >> 1) & 3)) << 4;
  const int w1base = ((wn * 64 + l15) << 6) + swf;  // + nt*1024
  const int w2base = ((w * 64 + l15) << 6) + swf;   // + mt*1024

  // ---- staging: wave-uniform LDS dest, per-lane pre-swizzled global src ----
  auto stageW1 = [&](int cc, int kk, unsigned char* buf) {  // 2 gll/wave
    const unsigned char* s = w1t + (((cc << 3) + kk) << 13) + (w << 11) + lo16;
    unsigned char* d = buf + (w << 11);
    gll16(s, d);
    gll16(s + 1024, d + 1024);
  };
  auto stageW2 = [&](int cc, int k2, unsigned char* buf) {  // 4 gll/wave
    const unsigned char* s = w2t + (((cc << 2) + k2) << 14) + (w << 12) + lo16;
    unsigned char* d = buf + (w << 12);
    gll16(s, d);               gll16(s + 1024, d + 1024);
    gll16(s + 2048, d + 2048); gll16(s + 3072, d + 3072);
  };

  // prologue: stage first W1 step, then full drain once (b1lds + stage all
  // visible). Costs one prefetch depth on the first step only.
  stageW1(0, 0, w1b0);
  __syncthreads();

#pragma unroll 1
  for (int c = 0; c < 8; ++c) {
    // h accumulators, init b1 (fp32 from LDS)
    floatx4 hacc[2][4];
#pragma unroll
    for (int nt = 0; nt < 4; ++nt) {
      const float bv = b1lds[c * 128 + wn * 64 + nt * 16 + l15];
      const floatx4 bb = {bv, bv, bv, bv};
      hacc[0][nt] = bb; hacc[1][nt] = bb;
    }

    // ---------------- GEMM1: 8 K-steps of 32 ----------------
#pragma unroll
    for (int k = 0; k < 8; ++k) {
      if (k < 7) {
        stageW1(c, k + 1, ((k + 1) & 1) ? w1b1 : w1b0);
        asm volatile("s_waitcnt vmcnt(2)" ::: "memory");   // step k landed
      } else {
        stageW2(c, 0, w2b0);
        asm volatile("s_waitcnt vmcnt(4)" ::: "memory");
      }
      barrier_fenced();   // all waves' step-k DMA visible

      const unsigned char* rb = (k & 1) ? w1b1 : w1b0;
      bf16x8 bfrag[4];
#pragma unroll
      for (int nt = 0; nt < 4; ++nt)
        bfrag[nt] = *(const bf16x8*)(rb + w1base + nt * 1024);
      __builtin_amdgcn_s_setprio(1);
#pragma unroll
      for (int mt = 0; mt < 2; ++mt)
#pragma unroll
        for (int nt = 0; nt < 4; ++nt)
          hacc[mt][nt] = __builtin_amdgcn_mfma_f32_16x16x32_bf16(
              xfrag[mt][k], bfrag[nt], hacc[mt][nt], 0, 0, 0);
      __builtin_amdgcn_s_setprio(0);
      barrier_fenced();   // readers done -> buffer reusable
    }

    // -------- GELU + h -> LDS (overlaps W2k0 load latency) --------
#pragma unroll
    for (int mt = 0; mt < 2; ++mt)
#pragma unroll
      for (int nt = 0; nt < 4; ++nt) {
        const int jl = wn * 64 + nt * 16 + l15;
        const int q  = jl >> 3;
        const int jo = (jl & 7) * 2;
#pragma unroll
        for (int r = 0; r < 4; ++r) {
          const float g = gelu_exact(hacc[mt][nt][r]);
          const int b = wm * 32 + mt * 16 + l4 * 4 + r;
          *(unsigned short*)(hlds + b * 256 + ((q ^ (b & 7)) * 16) + jo) = f2bf(g);
        }
      }

    // ---------------- GEMM2: 4 K-steps of 32 ----------------
#pragma unroll
    for (int k2 = 0; k2 < 4; ++k2) {
      if (k2 < 3) {
        stageW2(c, k2 + 1, ((k2 + 1) & 1) ? w2b1 : w2b0);
        if (k2 == 0)  // also drain own h ds_writes before barrier
          asm volatile("s_waitcnt vmcnt(4) lgkmcnt(0)" ::: "memory");
        else
          asm volatile("s_waitcnt vmcnt(4)" ::: "memory");
      } else {
        if (c < 7) {
          stageW1(c + 1, 0, w1b0);
          asm volatile("s_waitcnt vmcnt(2)" ::: "memory");
        } else {
          asm volatile("s_waitcnt vmcnt(0)" ::: "memory");
        }
      }
      barrier_fenced();

      const unsigned char* rb = (k2 & 1) ? w2b1 : w2b0;
      bf16x8 afrag[4];
#pragma unroll
      for (int mt = 0; mt < 4; ++mt)
        afrag[mt] = *(const bf16x8*)(rb + w2base + mt * 1024);
      bf16x8 hfrag[4];
#pragma unroll
      for (int nt = 0; nt < 4; ++nt)
        hfrag[nt] = *(const bf16x8*)(hlds + (nt * 16 + l15) * 256 +
                                     (((k2 * 4 + l4) ^ (lane & 7)) * 16));
      __builtin_amdgcn_s_setprio(1);
#pragma unroll
      for (int mt = 0; mt < 4; ++mt)
#pragma unroll
        for (int nt = 0; nt < 4; ++nt)
          oacc[mt][nt] = __builtin_amdgcn_mfma_f32_16x16x32_bf16(
              afrag[mt], hfrag[nt], oacc[mt][nt], 0, 0, 0);
      __builtin_amdgcn_s_setprio(0);
      barrier_fenced();
    }
  }

  // ---- epilogue: out^T regs -> out[b][t][d] ----
#pragma unroll
  for (int mt = 0; mt < 4; ++mt) {
    const int d = w * 64 + mt * 16 + l4 * 4;
#pragma unroll
    for (int nt = 0; nt < 4; ++nt) {
      const int b = b0 + nt * 16 + l15;
      *(floatx4*)(out + ((size_t)b * 64 + t) * 256 + d) = oacc[mt][nt];
    }
  }
}

// ---------------------------------------------------------------------------
// Round-0 verified kernel, kept verbatim as fallback if ws_size < 64 MB.
// ---------------------------------------------------------------------------
__global__ __launch_bounds__(256, 2) void mlp_kernel(
    const float* __restrict__ x, const float* __restrict__ w1,
    const float* __restrict__ b1, const float* __restrict__ w2,
    const float* __restrict__ b2, float* __restrict__ out) {

  __shared__ __attribute__((aligned(16))) unsigned char lds[40960];
  unsigned char* const w1img = lds;
  unsigned char* const w2img = lds + 8192;
  unsigned char* const hlds  = lds + 24576;

  const int tid  = threadIdx.x;
  const int lane = tid & 63;
  const int w    = tid >> 6;
  const int wm   = w >> 1;
  const int wn   = w & 1;
  const int l15  = lane & 15;
  const int l4   = lane >> 4;

  const int bid  = blockIdx.x;
  const int t    = (bid & 7) + 8 * (bid >> 9);
  const int b0   = ((bid >> 3) & 63) << 6;

  const float* w1t = w1 + (size_t)t * 262144;
  const float* w2t = w2 + (size_t)t * 262144;

  const int jl_s   = tid & 127;
  const int half_s = tid >> 7;
  const int P_s    = half_s ^ ((jl_s >> 2) & 1);
  const int sw2s   = (tid >> 1) & 3;

  bf16x8 xfrag[2][8];
#pragma unroll
  for (int mt = 0; mt < 2; ++mt) {
    const int b = b0 + wm * 32 + mt * 16 + l15;
    const float* xb = x + ((size_t)b * 64 + t) * 256 + l4 * 8;
#pragma unroll
    for (int kk = 0; kk < 8; ++kk) {
      floatx4 lo = *(const floatx4*)(xb + kk * 32);
      floatx4 hi = *(const floatx4*)(xb + kk * 32 + 4);
      union { bf16x8 v; unsigned short s[8]; } px;
      px.s[0] = f2bf(lo[0]); px.s[1] = f2bf(lo[1]);
      px.s[2] = f2bf(lo[2]); px.s[3] = f2bf(lo[3]);
      px.s[4] = f2bf(hi[0]); px.s[5] = f2bf(hi[1]);
      px.s[6] = f2bf(hi[2]); px.s[7] = f2bf(hi[3]);
      xfrag[mt][kk] = px.v;
    }
  }

  floatx4 oacc[4][4];
#pragma unroll
  for (int mt = 0; mt < 4; ++mt) {
    const floatx4 bv = *(const floatx4*)(b2 + t * 256 + w * 64 + mt * 16 + l4 * 4);
#pragma unroll
    for (int nt = 0; nt < 4; ++nt) oacc[mt][nt] = bv;
  }

  const int swf    = (l4 ^ ((lane >> 1) & 3)) << 4;
  const int w1base = ((wn * 64 + l15) << 6) + swf;
  const int w2base = ((w * 64 + l15) << 6) + swf;

#pragma unroll 1
  for (int c = 0; c < 8; ++c) {
    floatx4 hacc[2][4];
#pragma unroll
    for (int nt = 0; nt < 4; ++nt) {
      const float bv = b1[t * 1024 + c * 128 + wn * 64 + nt * 16 + l15];
      const floatx4 bb = {bv, bv, bv, bv};
      hacc[0][nt] = bb; hacc[1][nt] = bb;
    }

#pragma unroll
    for (int kk = 0; kk < 8; ++kk) {
      float f[16];
      const float* src = w1t + (size_t)(kk * 32 + half_s * 16) * 1024 + c * 128 + jl_s;
#pragma unroll
      for (int u = 0; u < 16; ++u) f[u] = src[(size_t)u * 1024];

      __syncthreads();
      union { uint4 v; unsigned short s[8]; } pk[2];
#pragma unroll
      for (int u = 0; u < 16; ++u) pk[u >> 3].s[u & 7] = f2bf(f[u]);
#pragma unroll
      for (int p = 0; p < 2; ++p) {
        const int m = 2 * P_s + p;
        const int s = (p ^ (jl_s >> 1)) & 1;
        *(uint4*)(w1img + jl_s * 64 + m * 16) = pk[s].v;
      }
      __syncthreads();

      bf16x8 bfrag[4];
#pragma unroll
      for (int nt = 0; nt < 4; ++nt)
        bfrag[nt] = *(const bf16x8*)(w1img + w1base + nt * 1024);
#pragma unroll
      for (int mt = 0; mt < 2; ++mt)
#pragma unroll
        for (int nt = 0; nt < 4; ++nt)
          hacc[mt][nt] = __builtin_amdgcn_mfma_f32_16x16x32_bf16(
              xfrag[mt][kk], bfrag[nt], hacc[mt][nt], 0, 0, 0);
    }

#pragma unroll
    for (int mt = 0; mt < 2; ++mt) {
#pragma unroll
      for (int nt = 0; nt < 4; ++nt) {
        const int jl = wn * 64 + nt * 16 + l15;
        const int q  = jl >> 3;
        const int jo = (jl & 7) * 2;
#pragma unroll
        for (int r = 0; r < 4; ++r) {
          const float g = gelu_exact(hacc[mt][nt][r]);
          const int b = wm * 32 + mt * 16 + l4 * 4 + r;
          *(unsigned short*)(hlds + b * 256 + ((q ^ (b & 7)) * 16) + jo) = f2bf(g);
        }
      }
    }

#pragma unroll
    for (int kk2 = 0; kk2 < 4; ++kk2) {
      float g2[32];
      const float* src2 = w2t + (size_t)(c * 128 + kk2 * 32) * 256 + tid;
#pragma unroll
      for (int v = 0; v < 32; ++v) g2[v] = src2[(size_t)v * 256];

      __syncthreads();
      union { uint4 v; unsigned short s[8]; } pk2[4];
#pragma unroll
      for (int v = 0; v < 32; ++v) pk2[v >> 3].s[v & 7] = f2bf(g2[v]);
#pragma unroll
      for (int p = 0; p < 4; ++p) {
        const int m = (p + (tid >> 1)) & 3;
        const int q = m ^ sw2s;
        *(uint4*)(w2img + tid * 64 + m * 16) = pk2[q].v;
      }
      __syncthreads();

      bf16x8 afrag[4];
#pragma unroll
      for (int mt = 0; mt < 4; ++mt)
        afrag[mt] = *(const bf16x8*)(w2img + w2base + mt * 1024);
      bf16x8 hfrag[4];
#pragma unroll
      for (int nt = 0; nt < 4; ++nt)
        hfrag[nt] = *(const bf16x8*)(hlds + (nt * 16 + l15) * 256 +
                                     (((kk2 * 4 + l4) ^ (lane & 7)) * 16));
#pragma unroll
      for (int mt = 0; mt < 4; ++mt)
#pragma unroll
        for (int nt = 0; nt < 4; ++nt)
          oacc[mt][nt] = __builtin_amdgcn_mfma_f32_16x16x32_bf16(
              afrag[mt], hfrag[nt], oacc[mt][nt], 0, 0, 0);
    }
  }

#pragma unroll
  for (int mt = 0; mt < 4; ++mt) {
    const int d = w * 64 + mt * 16 + l4 * 4;
#pragma unroll
    for (int nt = 0; nt < 4; ++nt) {
      const int b = b0 + nt * 16 + l15;
      *(floatx4*)(out + ((size_t)b * 64 + t) * 256 + d) = oacc[mt][nt];
    }
  }
}

// ---------------------------------------------------------------------------
extern "C" void kernel_launch(void* const* d_in, const int* in_sizes, int n_in,
                              void* d_out, int out_size, void* d_ws, size_t ws_size,
                              hipStream_t stream) {
  const float* x  = (const float*)d_in[0];
  const float* W1 = (const float*)d_in[1];
  const float* b1 = (const float*)d_in[2];
  const float* W2 = (const float*)d_in[3];
  const float* b2 = (const float*)d_in[4];
  float* out = (float*)d_out;

  const size_t need = 67108864;  // 32 MB W1 images + 32 MB W2 images
  if (d_ws != nullptr && ws_size >= need) {
    unsigned short* w1img = (unsigned short*)d_ws;
    unsigned short* w2img = (unsigned short*)((char*)d_ws + 33554432);
    prep_w1<<<8192, 256, 0, stream>>>(W1, w1img);
    prep_w2<<<8192, 256, 0, stream>>>(W2, w2img);
    mlp_fast<<<4096, 256, 0, stream>>>(x, w1img, b1, w2img, b2, out);
  } else {
    mlp_kernel<<<4096, 256, 0, stream>>>(x, W1, b1, W2, b2, out);
  }
}